// Round 3
// baseline (1429.494 us; speedup 1.0000x reference)
//
#include <hip/hip_runtime.h>
#include <hip/hip_bf16.h>

#define NROWS 20000
#define IPI 128
#define OPI 64
#define OPO 16

// ---------------- kernel 0: B = X @ W1  [N,128]x[128,64] ----------------
__global__ __launch_bounds__(256)
void k_xw1(const float* __restrict__ X, const float* __restrict__ W1,
           float* __restrict__ B) {
    __shared__ float w1[IPI * OPI];           // 32 KB
    const int t = threadIdx.x;
    for (int i = t * 4; i < IPI * OPI; i += 1024)
        *(float4*)&w1[i] = *(const float4*)&W1[i];
    __syncthreads();

    const int r  = blockIdx.x * 16 + (t >> 4);
    const int c4 = (t & 15) * 4;
    if (r >= NROWS) return;
    const float* xr = X + (size_t)r * IPI;
    float4 acc = make_float4(0.f, 0.f, 0.f, 0.f);
    #pragma unroll 8
    for (int k = 0; k < IPI; ++k) {
        const float x = xr[k];
        const float4 w = *(const float4*)&w1[k * OPI + c4];
        acc.x = fmaf(x, w.x, acc.x);
        acc.y = fmaf(x, w.y, acc.y);
        acc.z = fmaf(x, w.z, acc.z);
        acc.w = fmaf(x, w.w, acc.w);
    }
    *(float4*)&B[(size_t)r * OPI + c4] = acc;
}

// ---------------- k_gemm<NCOL>: Out[s] = A[:, kb:ke] @ Bm[kb:ke, :] -----
// block: 256 threads, tile = 64 rows x NCOL cols, K-chunk = KC per blockIdx.y
template<int NCOL>
__global__ __launch_bounds__(256)
void k_gemm(const float* __restrict__ A, const float* __restrict__ Bm,
            float* __restrict__ Out, int KC) {
    constexpr int CPT = NCOL / 16;            // cols per thread: 4 or 1
    __shared__ float lds_a[64 * 68];          // [k][row], stride 68 (16B-aligned, conflict-lite)
    __shared__ float lds_b[64 * NCOL];        // [k][col]
    const int t  = threadIdx.x;
    const int tr = t & 15;                    // compute: row group (4 rows)
    const int tc = t >> 4;                    // compute: col group
    const int brow    = blockIdx.x * 64;
    const int k_begin = blockIdx.y * KC;
    const int k_end   = min(NROWS, k_begin + KC);

    float acc[4][CPT];
    #pragma unroll
    for (int i = 0; i < 4; ++i)
        #pragma unroll
        for (int j = 0; j < CPT; ++j) acc[i][j] = 0.f;

    const int cl = (t & 15) * 4;              // staging: k offset within tile
    const int rl = t >> 4;                    // staging: row offset base

    for (int kt = k_begin; kt < k_end; kt += 64) {
        // stage A tile [64 rows][64 k] -> transposed lds_a[k][row]
        #pragma unroll
        for (int rr = 0; rr < 64; rr += 16) {
            const int row = brow + rl + rr;
            const int kg  = kt + cl;          // KC multiple of 4 -> whole float4 in/out of range
            float4 v = make_float4(0.f, 0.f, 0.f, 0.f);
            if (row < NROWS && kg < k_end)
                v = *(const float4*)&A[(size_t)row * NROWS + kg];
            lds_a[(cl + 0) * 68 + rl + rr] = v.x;
            lds_a[(cl + 1) * 68 + rl + rr] = v.y;
            lds_a[(cl + 2) * 68 + rl + rr] = v.z;
            lds_a[(cl + 3) * 68 + rl + rr] = v.w;
        }
        // stage B tile: rows kt..kt+63, contiguous in memory
        for (int i = t * 4; i < 64 * NCOL; i += 1024) {
            const int kg = kt + i / NCOL;
            float4 v = make_float4(0.f, 0.f, 0.f, 0.f);
            if (kg < k_end)
                v = *(const float4*)&Bm[(size_t)kt * NCOL + i];
            *(float4*)&lds_b[i] = v;
        }
        __syncthreads();

        #pragma unroll 8
        for (int k = 0; k < 64; ++k) {
            const float4 av = *(const float4*)&lds_a[k * 68 + tr * 4];
            const float a4[4] = {av.x, av.y, av.z, av.w};
            if constexpr (CPT == 4) {
                const float4 bv = *(const float4*)&lds_b[k * 64 + tc * 4];
                const float b4[4] = {bv.x, bv.y, bv.z, bv.w};
                #pragma unroll
                for (int i = 0; i < 4; ++i)
                    #pragma unroll
                    for (int j = 0; j < 4; ++j)
                        acc[i][j] = fmaf(a4[i], b4[j], acc[i][j]);
            } else {
                const float bz = lds_b[k * NCOL + tc];
                #pragma unroll
                for (int i = 0; i < 4; ++i)
                    acc[i][0] = fmaf(a4[i], bz, acc[i][0]);
            }
        }
        __syncthreads();
    }

    float* outp = Out + (size_t)blockIdx.y * NROWS * NCOL;
    #pragma unroll
    for (int i = 0; i < 4; ++i) {
        const int row = brow + tr * 4 + i;
        if (row < NROWS) {
            if constexpr (CPT == 4)
                *(float4*)&outp[(size_t)row * NCOL + tc * 4] =
                    make_float4(acc[i][0], acc[i][1], acc[i][2], acc[i][3]);
            else
                outp[(size_t)row * NCOL + tc] = acc[i][0];
        }
    }
}

// ------------- k_hw2: Z = relu(sum_s Hpart[s]) @ W2  [N,64]x[64,16] -----
__global__ __launch_bounds__(256)
void k_hw2(const float* __restrict__ Hpart, const float* __restrict__ W2,
           float* __restrict__ Z, int S1) {
    __shared__ float w2[OPI * OPO];           // 4 KB
    __shared__ float hs[16 * 68];             // 16 rows x 64 (+pad)
    const int t = threadIdx.x;
    if (t * 4 < OPI * OPO)
        *(float4*)&w2[t * 4] = *(const float4*)&W2[t * 4];

    const int r  = t >> 4;                    // 0..15
    const int c4 = (t & 15) * 4;              // 0..60
    const size_t rowg = (size_t)blockIdx.x * 16 + r;   // 1250*16 == 20000 exact

    float4 h = make_float4(0.f, 0.f, 0.f, 0.f);
    for (int s = 0; s < S1; ++s) {
        const float4 v = *(const float4*)&Hpart[((size_t)s * NROWS + rowg) * OPI + c4];
        h.x += v.x; h.y += v.y; h.z += v.z; h.w += v.w;
    }
    hs[r * 68 + c4 + 0] = fmaxf(h.x, 0.f);
    hs[r * 68 + c4 + 1] = fmaxf(h.y, 0.f);
    hs[r * 68 + c4 + 2] = fmaxf(h.z, 0.f);
    hs[r * 68 + c4 + 3] = fmaxf(h.w, 0.f);
    __syncthreads();

    const int c = t & 15;
    float z = 0.f;
    #pragma unroll 8
    for (int k = 0; k < OPI; ++k)
        z = fmaf(hs[r * 68 + k], w2[k * OPO + c], z);
    Z[rowg * OPO + c] = z;
}

// ------------- k_softmax: out = softmax(sum_s Lpart[s], axis=1) ---------
__global__ __launch_bounds__(256)
void k_softmax(const float* __restrict__ Lpart, float* __restrict__ out, int S2) {
    const int t = threadIdx.x;
    const size_t base = (size_t)blockIdx.x * 256;      // 16 rows x 16 cols
    float v = 0.f;
    for (int s = 0; s < S2; ++s)
        v += Lpart[(size_t)s * NROWS * OPO + base + t];
    float m = v;
    #pragma unroll
    for (int d = 8; d >= 1; d >>= 1) m = fmaxf(m, __shfl_xor(m, d, 16));
    const float e = expf(v - m);
    float sum = e;
    #pragma unroll
    for (int d = 8; d >= 1; d >>= 1) sum += __shfl_xor(sum, d, 16);
    out[base + t] = e / sum;
}

// ------------------------------------------------------------------------
extern "C" void kernel_launch(void* const* d_in, const int* in_sizes, int n_in,
                              void* d_out, int out_size, void* d_ws, size_t ws_size,
                              hipStream_t stream) {
    const float* A  = (const float*)d_in[0];
    const float* X  = (const float*)d_in[1];
    const float* W1 = (const float*)d_in[2];
    const float* W2 = (const float*)d_in[3];
    float* out = (float*)d_out;
    float* ws  = (float*)d_ws;

    // pick K-splits that fit the workspace (deterministic given ws_size)
    int S1 = 8, S2 = 8;
    auto need = [](int s1, int s2) -> size_t {
        return ((size_t)NROWS * OPI + (size_t)NROWS * OPO +
                (size_t)s1 * NROWS * OPI + (size_t)s2 * NROWS * OPO) * sizeof(float);
    };
    while ((S1 > 1 || S2 > 1) && need(S1, S2) > ws_size) {
        if (S1 > 1) S1 >>= 1;
        if (S2 > 1) S2 >>= 1;
    }

    float* B = ws;                              // [N][64]
    float* Z = B + (size_t)NROWS * OPI;         // [N][16]
    float* H = Z + (size_t)NROWS * OPO;         // [S1][N][64]
    float* L = H + (size_t)S1 * NROWS * OPI;    // [S2][N][16]

    const int MT = (NROWS + 63) / 64;           // 313
    const int KC1 = (((NROWS + S1 - 1) / S1) + 3) & ~3;
    const int KC2 = (((NROWS + S2 - 1) / S2) + 3) & ~3;

    k_xw1<<<dim3((NROWS + 15) / 16), 256, 0, stream>>>(X, W1, B);
    k_gemm<64><<<dim3(MT, S1), 256, 0, stream>>>(A, B, H, KC1);
    k_hw2<<<dim3(NROWS / 16), 256, 0, stream>>>(H, W2, Z, S1);
    k_gemm<16><<<dim3(MT, S2), 256, 0, stream>>>(A, Z, L, KC2);
    k_softmax<<<dim3(NROWS * OPO / 256), 256, 0, stream>>>(L, out, S2);
}